// Round 16
// baseline (952.912 us; speedup 1.0000x reference)
//
#include <hip/hip_runtime.h>
#include <hip/hip_bf16.h>
#include <math.h>

typedef __attribute__((ext_vector_type(8))) __bf16 bf16x8;
typedef __attribute__((ext_vector_type(4))) float f32x4;

// ---------------------------------------------------------------- helpers
__device__ __forceinline__ void stage16(const void* g, void* l) {
#if __has_builtin(__builtin_amdgcn_global_load_lds)
  __builtin_amdgcn_global_load_lds(
      (const __attribute__((address_space(1))) void*)g,
      (__attribute__((address_space(3))) void*)l, 16, 0, 0);
#else
  *(int4*)l = *(const int4*)g;
#endif
}

__device__ __forceinline__ float sigmoidf_(float x) {
  return 1.0f / (1.0f + __expf(-x));
}

__device__ __forceinline__ void f2b4(const float* __restrict__ s, __bf16* __restrict__ d) {
  float4 v = *(const float4*)s;
  union { __bf16 h[4]; int2 p; } u;
  u.h[0] = (__bf16)v.x; u.h[1] = (__bf16)v.y;
  u.h[2] = (__bf16)v.z; u.h[3] = (__bf16)v.w;
  *(int2*)d = u.p;
}

// ---------------------------------------------------------------- prep: all f32->bf16 + bias concat
__global__ __launch_bounds__(256) void prep(const float* __restrict__ x,
                                            const float* __restrict__ Wq,
                                            const float* __restrict__ Wk,
                                            const float* __restrict__ Wv,
                                            const float* __restrict__ Wo,
                                            const float* __restrict__ Wg,
                                            const float* __restrict__ bq,
                                            const float* __restrict__ bk,
                                            const float* __restrict__ bv,
                                            __bf16* __restrict__ XB,
                                            __bf16* __restrict__ WQKVb,
                                            __bf16* __restrict__ WOb,
                                            __bf16* __restrict__ WGb,
                                            float* __restrict__ BQKV) {
  int c = blockIdx.x * 256 + threadIdx.x;
  if (c >= 6820608) return;
  if (c < 4194304) {
    f2b4(x + (size_t)c * 4, XB + (size_t)c * 4);
  } else if (c < 5242880) {
    int e = (c - 4194304) * 4;  f2b4(Wq + e, WQKVb + e);
  } else if (c < 5505024) {
    int e = (c - 5242880) * 4;  f2b4(Wk + e, WQKVb + 4194304 + e);
  } else if (c < 5767168) {
    int e = (c - 5505024) * 4;  f2b4(Wv + e, WQKVb + 5242880 + e);
  } else if (c < 6815744) {
    int e = (c - 5767168) * 4;  f2b4(Wo + e, WOb + e);
  } else if (c < 6819840) {
    int e = (c - 6815744) * 4;  f2b4(Wg + e, WGb + e);
  } else {
    int e = (c - 6819840) * 4;
    float4 v;
    if (e < 2048)      v = *(const float4*)(bq + e);
    else if (e < 2560) v = *(const float4*)(bk + (e - 2048));
    else               v = *(const float4*)(bv + (e - 2560));
    *(float4*)(BQKV + e) = v;
  }
}

// ---------------------------------------------------------------- GEMM 256x256, 8-phase
template <typename OutT>
__global__ __launch_bounds__(512, 1) void gemm256(const __bf16* __restrict__ A,
                                                  const __bf16* __restrict__ Bm,
                                                  const float* __restrict__ bias,
                                                  OutT* __restrict__ C,
                                                  int M, int N, int K, int gx) {
  __shared__ __align__(16) __bf16 Sm[2][2][2][128 * 64];
  const int tid = threadIdx.x, lane = tid & 63, wid = tid >> 6;
  const int wm = wid >> 2, wn = wid & 3;
  const int r = lane & 15, g4 = lane >> 4;
  const int nwg = gridDim.x, qx = nwg >> 3;
  const int wg = (blockIdx.x & 7) * qx + (blockIdx.x >> 3);
  const int m0 = (wg / gx) * 256, n0 = (wg % gx) * 256;

  f32x4 acc[8][4] = {};
  const int NT = K >> 6;

#define STAGE_HALF(buf, which, half, kt)                                          \
  {                                                                               \
    const __bf16* sp_ = (which) ? Bm : A;                                         \
    const int base_ = ((which) ? n0 : m0) + (half) * 128;                         \
    const int k0_ = (kt) << 6;                                                    \
    __bf16* dp_ = &Sm[buf][which][half][0];                                       \
    _Pragma("unroll") for (int i_ = 0; i_ < 2; ++i_) {                            \
      int c_ = i_ * 512 + tid;                                                    \
      int row_ = c_ >> 3, slot_ = c_ & 7;                                         \
      stage16(sp_ + (size_t)(base_ + row_) * K + k0_ + ((slot_ ^ (row_ & 7)) << 3), \
              dp_ + c_ * 8);                                                      \
    }                                                                             \
  }
#define LDSW(base, row, kk) \
  (*(const bf16x8*)&(base)[(row) * 64 + ((((kk) * 4 + g4) ^ ((row) & 7)) << 3)])

  STAGE_HALF(0, 0, 0, 0) STAGE_HALF(0, 0, 1, 0) STAGE_HALF(0, 1, 0, 0) STAGE_HALF(0, 1, 1, 0)

  const int brow = (wn & 1) * 64;
  bf16x8 af[4][2], bfr[2][2];

  for (int kt = 0; kt < NT; ++kt) {
    const int cur = kt & 1, nxt = cur ^ 1;
    const bool more = (kt + 1) < NT;
    const __bf16* Ah = &Sm[cur][0][wm][0];
    const __bf16* Bh = &Sm[cur][1][wn >> 1][0];

    if (more) STAGE_HALF(nxt, 0, 0, kt + 1)
    if (more) { asm volatile("s_waitcnt vmcnt(2)" ::: "memory"); }
    else      { asm volatile("s_waitcnt vmcnt(0)" ::: "memory"); }
    __builtin_amdgcn_s_barrier();
    asm volatile("" ::: "memory");
#pragma unroll
    for (int m = 0; m < 4; ++m)
#pragma unroll
      for (int kk = 0; kk < 2; ++kk) af[m][kk] = LDSW(Ah, m * 16 + r, kk);
#pragma unroll
    for (int n = 0; n < 2; ++n)
#pragma unroll
      for (int kk = 0; kk < 2; ++kk) bfr[n][kk] = LDSW(Bh, brow + n * 16 + r, kk);
    asm volatile("s_waitcnt lgkmcnt(0)" ::: "memory");
    __builtin_amdgcn_sched_barrier(0);
    __builtin_amdgcn_s_setprio(1);
#pragma unroll
    for (int m = 0; m < 4; ++m)
#pragma unroll
      for (int n = 0; n < 2; ++n)
#pragma unroll
        for (int kk = 0; kk < 2; ++kk)
          acc[m][n] = __builtin_amdgcn_mfma_f32_16x16x32_bf16(af[m][kk], bfr[n][kk],
                                                              acc[m][n], 0, 0, 0);
    __builtin_amdgcn_s_setprio(0);
    __builtin_amdgcn_s_barrier();

#pragma unroll
    for (int n = 0; n < 2; ++n)
#pragma unroll
      for (int kk = 0; kk < 2; ++kk) bfr[n][kk] = LDSW(Bh, brow + (2 + n) * 16 + r, kk);
    if (more) STAGE_HALF(nxt, 0, 1, kt + 1)
    asm volatile("s_waitcnt lgkmcnt(0)" ::: "memory");
    __builtin_amdgcn_sched_barrier(0);
    __builtin_amdgcn_s_setprio(1);
#pragma unroll
    for (int m = 0; m < 4; ++m)
#pragma unroll
      for (int n = 0; n < 2; ++n)
#pragma unroll
        for (int kk = 0; kk < 2; ++kk)
          acc[m][2 + n] = __builtin_amdgcn_mfma_f32_16x16x32_bf16(af[m][kk], bfr[n][kk],
                                                                  acc[m][2 + n], 0, 0, 0);
    __builtin_amdgcn_s_setprio(0);
    __builtin_amdgcn_s_barrier();

#pragma unroll
    for (int m = 0; m < 4; ++m)
#pragma unroll
      for (int kk = 0; kk < 2; ++kk) af[m][kk] = LDSW(Ah, (4 + m) * 16 + r, kk);
#pragma unroll
    for (int n = 0; n < 2; ++n)
#pragma unroll
      for (int kk = 0; kk < 2; ++kk) bfr[n][kk] = LDSW(Bh, brow + n * 16 + r, kk);
    if (more) STAGE_HALF(nxt, 1, 0, kt + 1)
    asm volatile("s_waitcnt lgkmcnt(0)" ::: "memory");
    __builtin_amdgcn_sched_barrier(0);
    __builtin_amdgcn_s_setprio(1);
#pragma unroll
    for (int m = 0; m < 4; ++m)
#pragma unroll
      for (int n = 0; n < 2; ++n)
#pragma unroll
        for (int kk = 0; kk < 2; ++kk)
          acc[4 + m][n] = __builtin_amdgcn_mfma_f32_16x16x32_bf16(af[m][kk], bfr[n][kk],
                                                                  acc[4 + m][n], 0, 0, 0);
    __builtin_amdgcn_s_setprio(0);
    __builtin_amdgcn_s_barrier();

#pragma unroll
    for (int n = 0; n < 2; ++n)
#pragma unroll
      for (int kk = 0; kk < 2; ++kk) bfr[n][kk] = LDSW(Bh, brow + (2 + n) * 16 + r, kk);
    if (more) STAGE_HALF(nxt, 1, 1, kt + 1)
    asm volatile("s_waitcnt lgkmcnt(0)" ::: "memory");
    __builtin_amdgcn_sched_barrier(0);
    __builtin_amdgcn_s_setprio(1);
#pragma unroll
    for (int m = 0; m < 4; ++m)
#pragma unroll
      for (int n = 0; n < 2; ++n)
#pragma unroll
        for (int kk = 0; kk < 2; ++kk)
          acc[4 + m][2 + n] = __builtin_amdgcn_mfma_f32_16x16x32_bf16(af[m][kk], bfr[n][kk],
                                                                      acc[4 + m][2 + n], 0, 0, 0);
    __builtin_amdgcn_s_setprio(0);
    __builtin_amdgcn_s_barrier();
  }

  const int rq = lane >> 4;
#pragma unroll
  for (int m = 0; m < 8; ++m)
#pragma unroll
    for (int n = 0; n < 4; ++n) {
      int col = n0 + wn * 64 + n * 16 + r;
      float bv = bias ? bias[col] : 0.0f;
#pragma unroll
      for (int j = 0; j < 4; ++j) {
        int row = m0 + wm * 128 + m * 16 + rq * 4 + j;
        C[(size_t)row * N + col] = (OutT)(acc[m][n][j] + bv);
      }
    }
#undef STAGE_HALF
#undef LDSW
}

// ---------------------------------------------------------------- RoPE+RMSNorm (q,k) + V transpose
__global__ __launch_bounds__(256) void rope_vt(const __bf16* __restrict__ Y,
                                               const float* __restrict__ cosT,
                                               const float* __restrict__ sinT,
                                               const float* __restrict__ qn,
                                               const float* __restrict__ kn,
                                               __bf16* __restrict__ qat,
                                               __bf16* __restrict__ kat,
                                               __bf16* __restrict__ VT) {
  __shared__ __bf16 tile[32][66];
  if (blockIdx.x < 8192) {
    const int tok = blockIdx.x;
    const int b = tok >> 11, t = tok & 2047;
    const int wv = threadIdx.x >> 6, l = threadIdx.x & 63;
    const __bf16* row = Y + (size_t)tok * 3072;
    const float c = cosT[t * 64 + l], s = sinT[t * 64 + l];
    const float QS = 0.08838834764831845f * 1.4426950408889634f;
#pragma unroll
    for (int i = 0; i < 5; ++i) {
      const int h = wv + i * 4;  // 0..19
      const bool isq = h < 16;
      const int base = isq ? h * 128 : 2048 + (h - 16) * 128;
      union { uint32_t u; __bf16 h2[2]; } p;
      p.u = *(const uint32_t*)(row + base + 2 * l);
      float x1 = (float)p.h2[0], x2 = (float)p.h2[1];
      float v1 = x1 * c - x2 * s;
      float v2 = x1 * s + x2 * c;
      float ss = v1 * v1 + v2 * v2;
#pragma unroll
      for (int o = 32; o >= 1; o >>= 1) ss += __shfl_xor(ss, o, 64);
      float rms = rsqrtf(ss * (1.0f / 128.0f) + 1e-6f);
      if (isq) rms *= QS;
      float w1 = isq ? qn[l] : kn[l];
      float w2 = isq ? qn[64 + l] : kn[64 + l];
      size_t ob = isq ? (((size_t)b * 16 + h) * 2048 + t) * 128
                      : (((size_t)b * 4 + (h - 16)) * 2048 + t) * 128;
      __bf16* dst = isq ? qat : kat;
      dst[ob + l] = (__bf16)(w1 * v1 * rms);
      dst[ob + 64 + l] = (__bf16)(w2 * v2 * rms);
    }
  } else {
    const int i = blockIdx.x - 8192;
    const int t0 = (i & 31) * 64;
    const int d0 = ((i >> 5) & 3) * 32;
    const int bh = i >> 7;
    const int b = bh >> 2, hv = bh & 3;
    const __bf16* src = Y + (size_t)b * 2048 * 3072 + 2560 + hv * 128 + d0;
    const int dd = threadIdx.x & 31, tt = threadIdx.x >> 5;
#pragma unroll
    for (int p = 0; p < 8; ++p) {
      int t = tt + p * 8;
      tile[dd][t] = src[(size_t)(t0 + t) * 3072 + dd];
    }
    __syncthreads();
    __bf16* dst = VT + ((size_t)bh * 128 + d0) * 2048 + t0;
    const int oc = threadIdx.x & 63, orr = threadIdx.x >> 6;
#pragma unroll
    for (int p = 0; p < 8; ++p) {
      int d = orr + p * 4;
      dst[(size_t)d * 2048 + oc] = tile[d][oc];
    }
  }
}

// ---------------------------------------------------------------- flash attention (causal, GQA)
// KVBLK=32, 4 waves x 32 q-rows (QBLK=128), one q-tile per block, grid 1024
// (descending qt) -> 4 blocks/CU co-resident (40 KB LDS). exp2 softmax,
// MFMA row-sum, lazy max, XOR-swizzled K/V/P tiles.
__global__ __launch_bounds__(256, 4) void attn12(const __bf16* __restrict__ Q,
                                                 const __bf16* __restrict__ Kg,
                                                 const __bf16* __restrict__ VTg,
                                                 __bf16* __restrict__ ab) {
  __shared__ __align__(16) __bf16 Kt[2][32 * 128];   // 16 KB
  __shared__ __align__(16) __bf16 Vt[2][128 * 32];   // 16 KB
  __shared__ __align__(16) __bf16 Ps[4 * 32 * 32];   // 8 KB
  const int tid = threadIdx.x, lane = tid & 63, wv = tid >> 6;  // wv 0..3
  const int L = blockIdx.x;
  const int xcd = L & 7, slot = L >> 3;                 // slot 0..127
  const int group = xcd * 2 + (slot >> 6);              // 16 (b,hkv) groups
  const int idx = slot & 63;
  const int b = group >> 2, hkv = group & 3;
  const int hq = hkv * 4 + (idx >> 4);
  const int qt = 15 - (idx & 15);                       // long q-tiles dispatch first
  const __bf16* qp = Q + ((size_t)b * 16 + hq) * 2048 * 128;
  const __bf16* kp = Kg + ((size_t)b * 4 + hkv) * 2048 * 128;
  const __bf16* vp = VTg + ((size_t)b * 4 + hkv) * 128 * 2048;
  const int r = lane & 15, g4 = lane >> 4, ks = g4 * 8;

  bf16x8 vone;
#pragma unroll
  for (int e = 0; e < 8; ++e) vone[e] = (__bf16)1.0f;

  // K: 512 chunks (32 rows x 16 slots, ^row&7); V^T: 512 chunks (128 rows x 4 slots, ^row&3)
#define STAGE_TILE(bi, kv0)                                                  \
  {                                                                          \
    __bf16* Kb = &Kt[bi][0];                                                 \
    __bf16* Vb = &Vt[bi][0];                                                 \
    _Pragma("unroll") for (int i = 0; i < 2; ++i) {                          \
      int c = i * 256 + tid;                                                 \
      int row = c >> 4, slot_ = c & 15;                                      \
      int gco = ((slot_ ^ (row & 7)) << 3);                                  \
      stage16(kp + (size_t)((kv0) + row) * 128 + gco, &Kb[c * 8]);           \
    }                                                                        \
    _Pragma("unroll") for (int i = 0; i < 2; ++i) {                          \
      int c = i * 256 + tid;                                                 \
      int row = c >> 2, slot_ = c & 3;                                       \
      int gco = ((slot_ ^ (row & 3)) << 3);                                  \
      stage16(vp + (size_t)row * 2048 + (kv0) + gco, &Vb[c * 8]);            \
    }                                                                        \
  }

  const int q0 = qt * 128 + wv * 32;  // wave owns rows q0..q0+31

  bf16x8 qfA[4], qfB[4];
#pragma unroll
  for (int kk = 0; kk < 4; ++kk) {
    qfA[kk] = *(const bf16x8*)(qp + (size_t)(q0 + r) * 128 + kk * 32 + ks);
    qfB[kk] = *(const bf16x8*)(qp + (size_t)(q0 + 16 + r) * 128 + kk * 32 + ks);
  }

  f32x4 OfA[8] = {}, OfB[8] = {};
  f32x4 LaccA = {}, LaccB = {};
  float mrowA[4] = {-1e30f, -1e30f, -1e30f, -1e30f};
  float mrowB[4] = {-1e30f, -1e30f, -1e30f, -1e30f};

  const int nt = 4 * qt + 4;
  STAGE_TILE(0, 0);
  int cur = 0;
  for (int t = 0; t < nt; ++t) {
    const int kv0 = t * 32;
    if (t + 1 < nt) {
      STAGE_TILE(cur ^ 1, (t + 1) * 32);
      asm volatile("s_waitcnt vmcnt(4)" ::: "memory");
    } else {
      asm volatile("s_waitcnt vmcnt(0)" ::: "memory");
    }
    __builtin_amdgcn_s_barrier();

    const __bf16* Kb = &Kt[cur][0];
    const __bf16* Vb = &Vt[cur][0];

    // QK^T: 2 kj tiles x both q-halves (K fragment shared)
    f32x4 sA[2], sB[2];
    __builtin_amdgcn_s_setprio(1);
#pragma unroll
    for (int kj = 0; kj < 2; ++kj) {
      f32x4 saA = {}, saB = {};
      int krow = kj * 16 + r;
#pragma unroll
      for (int kk = 0; kk < 4; ++kk) {
        int slot_ = (kk * 4 + g4) ^ (r & 7);
        bf16x8 kf = *(const bf16x8*)&Kb[krow * 128 + slot_ * 8];
        saA = __builtin_amdgcn_mfma_f32_16x16x32_bf16(qfA[kk], kf, saA, 0, 0, 0);
        saB = __builtin_amdgcn_mfma_f32_16x16x32_bf16(qfB[kk], kf, saB, 0, 0, 0);
      }
      sA[kj] = saA; sB[kj] = saB;
    }
    __builtin_amdgcn_s_setprio(0);
    if (kv0 + 31 > q0) {
#pragma unroll
      for (int kj = 0; kj < 2; ++kj)
#pragma unroll
        for (int j = 0; j < 4; ++j) {
          int kv = kv0 + kj * 16 + r;
          int qrA = q0 + g4 * 4 + j;
          if (kv > qrA) sA[kj][j] = -1e30f;
          if (kv > qrA + 16) sB[kj][j] = -1e30f;
        }
    }
    float tmA[4], tmB[4];
#pragma unroll
    for (int j = 0; j < 4; ++j) {
      tmA[j] = fmaxf(sA[0][j], sA[1][j]);
      tmB[j] = fmaxf(sB[0][j], sB[1][j]);
    }
    bool need = false;
#pragma unroll
    for (int j = 0; j < 4; ++j)
      need |= (tmA[j] > mrowA[j] + 8.0f) | (tmB[j] > mrowB[j] + 8.0f);
    if (__any(need)) {
#pragma unroll
      for (int o = 8; o >= 1; o >>= 1)
#pragma unroll
        for (int j = 0; j < 4; ++j) {
          tmA[j] = fmaxf(tmA[j], __shfl_xor(tmA[j], o, 64));
          tmB[j] = fmaxf(tmB[j], __shfl_xor(tmB[j], o, 64));
        }
#pragma unroll
      for (int j = 0; j < 4; ++j) {
        float mnA = fmaxf(mrowA[j], tmA[j]);
        float cA = exp2f(mrowA[j] - mnA);
        mrowA[j] = mnA; LaccA[j] *= cA;
        float mnB = fmaxf(mrowB[j], tmB[j]);
        float cB = exp2f(mrowB[j] - mnB);
        mrowB[j] = mnB; LaccB[j] *= cB;
#pragma unroll
        for (int f = 0; f < 8; ++f) { OfA[f][j] *= cA; OfB[f][j] *= cB; }
      }
    }
    // exp2 + pack into Ps (wave-private [32][32], slot ^= row&3)
    __bf16* pw = &Ps[wv * 32 * 32];
#pragma unroll
    for (int kj = 0; kj < 2; ++kj)
#pragma unroll
      for (int j = 0; j < 4; ++j) {
        int kvl = kj * 16 + r;
        int qrA = g4 * 4 + j;
        int slA = (kvl >> 3) ^ (qrA & 3);
        pw[qrA * 32 + slA * 8 + (kvl & 7)] = (__bf16)exp2f(sA[kj][j] - mrowA[j]);
        int qrB = 16 + qrA;
        int slB = (kvl >> 3) ^ (qrB & 3);
        pw[qrB * 32 + slB * 8 + (kvl & 7)] = (__bf16)exp2f(sB[kj][j] - mrowB[j]);
      }
    // PV: single 32-kv chunk, V fragment shared across halves
    __builtin_amdgcn_s_setprio(1);
    {
      int sl = g4 ^ (r & 3);
      bf16x8 paA = *(const bf16x8*)&pw[r * 32 + sl * 8];
      bf16x8 paB = *(const bf16x8*)&pw[(16 + r) * 32 + sl * 8];
      LaccA = __builtin_amdgcn_mfma_f32_16x16x32_bf16(paA, vone, LaccA, 0, 0, 0);
      LaccB = __builtin_amdgcn_mfma_f32_16x16x32_bf16(paB, vone, LaccB, 0, 0, 0);
#pragma unroll
      for (int dn = 0; dn < 8; ++dn) {
        int vrow = dn * 16 + r;
        bf16x8 vb = *(const bf16x8*)&Vb[vrow * 32 + ((g4 ^ (r & 3)) << 3)];
        OfA[dn] = __builtin_amdgcn_mfma_f32_16x16x32_bf16(paA, vb, OfA[dn], 0, 0, 0);
        OfB[dn] = __builtin_amdgcn_mfma_f32_16x16x32_bf16(paB, vb, OfB[dn], 0, 0, 0);
      }
    }
    __builtin_amdgcn_s_setprio(0);
    __builtin_amdgcn_s_barrier();
    cur ^= 1;
  }

  float invA[4], invB[4];
#pragma unroll
  for (int j = 0; j < 4; ++j) { invA[j] = 1.0f / LaccA[j]; invB[j] = 1.0f / LaccB[j]; }
#pragma unroll
  for (int dn = 0; dn < 8; ++dn)
#pragma unroll
    for (int j = 0; j < 4; ++j) {
      int rowA = q0 + g4 * 4 + j;
      int d = dn * 16 + r;
      ab[(((size_t)b * 2048 + rowA) * 16 + hq) * 128 + d] = (__bf16)(OfA[dn][j] * invA[j]);
      ab[(((size_t)b * 2048 + rowA + 16) * 16 + hq) * 128 + d] = (__bf16)(OfB[dn][j] * invB[j]);
    }
#undef STAGE_TILE
}

// ---------------------------------------------------------------- fused gate
__global__ __launch_bounds__(256) void gate_fused(const __bf16* __restrict__ a,
                                                  const __bf16* __restrict__ WgB,
                                                  const float* __restrict__ bg,
                                                  __bf16* __restrict__ og) {
  __shared__ __align__(16) __bf16 Wl[128 * 128];
  const int tid = threadIdx.x, lane = tid & 63, wv = tid >> 6;
  const int r = lane & 15, g4 = lane >> 4, ks = g4 * 8;
#pragma unroll
  for (int i = 0; i < 8; ++i) {
    int c = i * 256 + tid;
    int row = c >> 4, slot = c & 15;
    *(bf16x8*)&Wl[row * 128 + ((slot ^ (row & 7)) << 3)] =
        *(const bf16x8*)&WgB[row * 128 + slot * 8];
  }
  __syncthreads();
  const size_t r0 = (size_t)blockIdx.x * 64 + wv * 16;
  bf16x8 af[4];
#pragma unroll
  for (int kk = 0; kk < 4; ++kk)
    af[kk] = *(const bf16x8*)(a + (r0 + r) * 128 + kk * 32 + ks);
  f32x4 acc[8] = {};
#pragma unroll
  for (int dn = 0; dn < 8; ++dn) {
    int row = dn * 16 + r;
#pragma unroll
    for (int kk = 0; kk < 4; ++kk) {
      bf16x8 bf_ = *(const bf16x8*)&Wl[row * 128 + (((kk * 4 + g4) ^ (row & 7)) << 3)];
      acc[dn] = __builtin_amdgcn_mfma_f32_16x16x32_bf16(af[kk], bf_, acc[dn], 0, 0, 0);
    }
  }
#pragma unroll
  for (int dn = 0; dn < 8; ++dn) {
    float bgv = bg[dn * 16 + r];
#pragma unroll
    for (int j = 0; j < 4; ++j) {
      size_t row = r0 + g4 * 4 + j;
      int col = dn * 16 + r;
      float gv = sigmoidf_(acc[dn][j] + bgv);
      float av = (float)a[row * 128 + col];
      og[row * 128 + col] = (__bf16)(av * gv);
    }
  }
}

// ---------------------------------------------------------------- launch
extern "C" void kernel_launch(void* const* d_in, const int* in_sizes, int n_in,
                              void* d_out, int out_size, void* d_ws, size_t ws_size,
                              hipStream_t stream) {
  const float* x    = (const float*)d_in[0];
  const float* Wq   = (const float*)d_in[1];
  const float* bq   = (const float*)d_in[2];
  const float* Wk   = (const float*)d_in[3];
  const float* bk   = (const float*)d_in[4];
  const float* Wv   = (const float*)d_in[5];
  const float* bv   = (const float*)d_in[6];
  const float* qn   = (const float*)d_in[7];
  const float* kn   = (const float*)d_in[8];
  const float* Wg   = (const float*)d_in[9];
  const float* bg   = (const float*)d_in[10];
  const float* Wo   = (const float*)d_in[11];
  const float* bo   = (const float*)d_in[12];
  const float* cosT = (const float*)d_in[13];
  const float* sinT = (const float*)d_in[14];

  char* ws = (char*)d_ws;
  constexpr size_t OFF_WQKV = 0;                                   // 3072x2048 bf16
  constexpr size_t OFF_WO   = OFF_WQKV + 3072ull * 2048 * 2;       // 2048x2048 bf16
  constexpr size_t OFF_WG   = OFF_WO + 2048ull * 2048 * 2;         // 128x128 bf16
  constexpr size_t OFF_BQKV = OFF_WG + 128ull * 128 * 2;           // 3072 f32 (+pad)
  constexpr size_t OFF_XB   = OFF_BQKV + 16384;                    // 8192x2048 bf16 (reused: OG)
  constexpr size_t OFF_Y    = OFF_XB + 8192ull * 2048 * 2;         // 8192x3072 bf16
  constexpr size_t OFF_QAT  = OFF_Y + 8192ull * 3072 * 2;          // (B,HQ,T,D) bf16
  constexpr size_t OFF_KAT  = OFF_QAT + 4ull * 16 * 2048 * 128 * 2;
  constexpr size_t OFF_VT   = OFF_KAT + 4ull * 4 * 2048 * 128 * 2; // (B,HKV,D,T) bf16
  constexpr size_t OFF_AB   = OFF_VT + 4ull * 4 * 2048 * 128 * 2;  // (B,T,HQ,D) bf16

  __bf16* WQKVb = (__bf16*)(ws + OFF_WQKV);
  __bf16* WOb   = (__bf16*)(ws + OFF_WO);
  __bf16* WGb   = (__bf16*)(ws + OFF_WG);
  float*  BQKV  = (float*)(ws + OFF_BQKV);
  __bf16* XB    = (__bf16*)(ws + OFF_XB);
  __bf16* Y     = (__bf16*)(ws + OFF_Y);
  __bf16* QAT   = (__bf16*)(ws + OFF_QAT);
  __bf16* KAT   = (__bf16*)(ws + OFF_KAT);
  __bf16* VT    = (__bf16*)(ws + OFF_VT);
  __bf16* ABuf  = (__bf16*)(ws + OFF_AB);
  __bf16* OGB   = (__bf16*)(ws + OFF_XB);   // reuse XB (dead after QKV GEMM)

  prep<<<26643, 256, 0, stream>>>(x, Wq, Wk, Wv, Wo, Wg, bq, bk, bv,
                                  XB, WQKVb, WOb, WGb, BQKV);

  // QKV projection: 256^2 8-phase, 384 blocks
  gemm256<__bf16><<<384, 512, 0, stream>>>(XB, WQKVb, BQKV, Y, 8192, 3072, 2048, 12);

  // RoPE+RMSNorm (q,k; Q pre-scaled) + V transpose
  rope_vt<<<10240, 256, 0, stream>>>(Y, cosT, sinT, qn, kn, QAT, KAT, VT);

  // flash attention: KVBLK=32, 1024 blocks, 4 blocks/CU
  attn12<<<1024, 256, 0, stream>>>(QAT, KAT, VT, ABuf);

  // fused gate
  gate_fused<<<2048, 256, 0, stream>>>(ABuf, WGb, bg, OGB);

  // output projection: 256^2, 256 blocks = 1 full round
  gemm256<float><<<256, 512, 0, stream>>>(OGB, WOb, bo, (float*)d_out, 8192, 2048, 2048, 8);
}

// Round 17
// 440.832 us; speedup vs baseline: 2.1616x; 2.1616x over previous
//
#include <hip/hip_runtime.h>
#include <hip/hip_bf16.h>
#include <math.h>

typedef __attribute__((ext_vector_type(8))) __bf16 bf16x8;
typedef __attribute__((ext_vector_type(4))) float f32x4;

// ---------------------------------------------------------------- helpers
__device__ __forceinline__ void stage16(const void* g, void* l) {
#if __has_builtin(__builtin_amdgcn_global_load_lds)
  __builtin_amdgcn_global_load_lds(
      (const __attribute__((address_space(1))) void*)g,
      (__attribute__((address_space(3))) void*)l, 16, 0, 0);
#else
  *(int4*)l = *(const int4*)g;
#endif
}

__device__ __forceinline__ float sigmoidf_(float x) {
  return 1.0f / (1.0f + __expf(-x));
}

__device__ __forceinline__ void f2b4(const float* __restrict__ s, __bf16* __restrict__ d) {
  float4 v = *(const float4*)s;
  union { __bf16 h[4]; int2 p; } u;
  u.h[0] = (__bf16)v.x; u.h[1] = (__bf16)v.y;
  u.h[2] = (__bf16)v.z; u.h[3] = (__bf16)v.w;
  *(int2*)d = u.p;
}

// ---------------------------------------------------------------- prep: all f32->bf16 + bias concat
__global__ __launch_bounds__(256) void prep(const float* __restrict__ x,
                                            const float* __restrict__ Wq,
                                            const float* __restrict__ Wk,
                                            const float* __restrict__ Wv,
                                            const float* __restrict__ Wo,
                                            const float* __restrict__ Wg,
                                            const float* __restrict__ bq,
                                            const float* __restrict__ bk,
                                            const float* __restrict__ bv,
                                            __bf16* __restrict__ XB,
                                            __bf16* __restrict__ WQKVb,
                                            __bf16* __restrict__ WOb,
                                            __bf16* __restrict__ WGb,
                                            float* __restrict__ BQKV) {
  int c = blockIdx.x * 256 + threadIdx.x;
  if (c >= 6820608) return;
  if (c < 4194304) {
    f2b4(x + (size_t)c * 4, XB + (size_t)c * 4);
  } else if (c < 5242880) {
    int e = (c - 4194304) * 4;  f2b4(Wq + e, WQKVb + e);
  } else if (c < 5505024) {
    int e = (c - 5242880) * 4;  f2b4(Wk + e, WQKVb + 4194304 + e);
  } else if (c < 5767168) {
    int e = (c - 5505024) * 4;  f2b4(Wv + e, WQKVb + 5242880 + e);
  } else if (c < 6815744) {
    int e = (c - 5767168) * 4;  f2b4(Wo + e, WOb + e);
  } else if (c < 6819840) {
    int e = (c - 6815744) * 4;  f2b4(Wg + e, WGb + e);
  } else {
    int e = (c - 6819840) * 4;
    float4 v;
    if (e < 2048)      v = *(const float4*)(bq + e);
    else if (e < 2560) v = *(const float4*)(bk + (e - 2048));
    else               v = *(const float4*)(bv + (e - 2560));
    *(float4*)(BQKV + e) = v;
  }
}

// ---------------------------------------------------------------- GEMM 256x256, 8-phase
template <typename OutT>
__global__ __launch_bounds__(512, 1) void gemm256(const __bf16* __restrict__ A,
                                                  const __bf16* __restrict__ Bm,
                                                  const float* __restrict__ bias,
                                                  OutT* __restrict__ C,
                                                  int M, int N, int K, int gx) {
  __shared__ __align__(16) __bf16 Sm[2][2][2][128 * 64];
  const int tid = threadIdx.x, lane = tid & 63, wid = tid >> 6;
  const int wm = wid >> 2, wn = wid & 3;
  const int r = lane & 15, g4 = lane >> 4;
  const int nwg = gridDim.x, qx = nwg >> 3;
  const int wg = (blockIdx.x & 7) * qx + (blockIdx.x >> 3);
  const int m0 = (wg / gx) * 256, n0 = (wg % gx) * 256;

  f32x4 acc[8][4] = {};
  const int NT = K >> 6;

#define STAGE_HALF(buf, which, half, kt)                                          \
  {                                                                               \
    const __bf16* sp_ = (which) ? Bm : A;                                         \
    const int base_ = ((which) ? n0 : m0) + (half) * 128;                         \
    const int k0_ = (kt) << 6;                                                    \
    __bf16* dp_ = &Sm[buf][which][half][0];                                       \
    _Pragma("unroll") for (int i_ = 0; i_ < 2; ++i_) {                            \
      int c_ = i_ * 512 + tid;                                                    \
      int row_ = c_ >> 3, slot_ = c_ & 7;                                         \
      stage16(sp_ + (size_t)(base_ + row_) * K + k0_ + ((slot_ ^ (row_ & 7)) << 3), \
              dp_ + c_ * 8);                                                      \
    }                                                                             \
  }
#define LDSW(base, row, kk) \
  (*(const bf16x8*)&(base)[(row) * 64 + ((((kk) * 4 + g4) ^ ((row) & 7)) << 3)])

  STAGE_HALF(0, 0, 0, 0) STAGE_HALF(0, 0, 1, 0) STAGE_HALF(0, 1, 0, 0) STAGE_HALF(0, 1, 1, 0)

  const int brow = (wn & 1) * 64;
  bf16x8 af[4][2], bfr[2][2];

  for (int kt = 0; kt < NT; ++kt) {
    const int cur = kt & 1, nxt = cur ^ 1;
    const bool more = (kt + 1) < NT;
    const __bf16* Ah = &Sm[cur][0][wm][0];
    const __bf16* Bh = &Sm[cur][1][wn >> 1][0];

    if (more) STAGE_HALF(nxt, 0, 0, kt + 1)
    if (more) { asm volatile("s_waitcnt vmcnt(2)" ::: "memory"); }
    else      { asm volatile("s_waitcnt vmcnt(0)" ::: "memory"); }
    __builtin_amdgcn_s_barrier();
    asm volatile("" ::: "memory");
#pragma unroll
    for (int m = 0; m < 4; ++m)
#pragma unroll
      for (int kk = 0; kk < 2; ++kk) af[m][kk] = LDSW(Ah, m * 16 + r, kk);
#pragma unroll
    for (int n = 0; n < 2; ++n)
#pragma unroll
      for (int kk = 0; kk < 2; ++kk) bfr[n][kk] = LDSW(Bh, brow + n * 16 + r, kk);
    asm volatile("s_waitcnt lgkmcnt(0)" ::: "memory");
    __builtin_amdgcn_sched_barrier(0);
    __builtin_amdgcn_s_setprio(1);
#pragma unroll
    for (int m = 0; m < 4; ++m)
#pragma unroll
      for (int n = 0; n < 2; ++n)
#pragma unroll
        for (int kk = 0; kk < 2; ++kk)
          acc[m][n] = __builtin_amdgcn_mfma_f32_16x16x32_bf16(af[m][kk], bfr[n][kk],
                                                              acc[m][n], 0, 0, 0);
    __builtin_amdgcn_s_setprio(0);
    __builtin_amdgcn_s_barrier();

#pragma unroll
    for (int n = 0; n < 2; ++n)
#pragma unroll
      for (int kk = 0; kk < 2; ++kk) bfr[n][kk] = LDSW(Bh, brow + (2 + n) * 16 + r, kk);
    if (more) STAGE_HALF(nxt, 0, 1, kt + 1)
    asm volatile("s_waitcnt lgkmcnt(0)" ::: "memory");
    __builtin_amdgcn_sched_barrier(0);
    __builtin_amdgcn_s_setprio(1);
#pragma unroll
    for (int m = 0; m < 4; ++m)
#pragma unroll
      for (int n = 0; n < 2; ++n)
#pragma unroll
        for (int kk = 0; kk < 2; ++kk)
          acc[m][2 + n] = __builtin_amdgcn_mfma_f32_16x16x32_bf16(af[m][kk], bfr[n][kk],
                                                                  acc[m][2 + n], 0, 0, 0);
    __builtin_amdgcn_s_setprio(0);
    __builtin_amdgcn_s_barrier();

#pragma unroll
    for (int m = 0; m < 4; ++m)
#pragma unroll
      for (int kk = 0; kk < 2; ++kk) af[m][kk] = LDSW(Ah, (4 + m) * 16 + r, kk);
#pragma unroll
    for (int n = 0; n < 2; ++n)
#pragma unroll
      for (int kk = 0; kk < 2; ++kk) bfr[n][kk] = LDSW(Bh, brow + n * 16 + r, kk);
    if (more) STAGE_HALF(nxt, 1, 0, kt + 1)
    asm volatile("s_waitcnt lgkmcnt(0)" ::: "memory");
    __builtin_amdgcn_sched_barrier(0);
    __builtin_amdgcn_s_setprio(1);
#pragma unroll
    for (int m = 0; m < 4; ++m)
#pragma unroll
      for (int n = 0; n < 2; ++n)
#pragma unroll
        for (int kk = 0; kk < 2; ++kk)
          acc[4 + m][n] = __builtin_amdgcn_mfma_f32_16x16x32_bf16(af[m][kk], bfr[n][kk],
                                                                  acc[4 + m][n], 0, 0, 0);
    __builtin_amdgcn_s_setprio(0);
    __builtin_amdgcn_s_barrier();

#pragma unroll
    for (int n = 0; n < 2; ++n)
#pragma unroll
      for (int kk = 0; kk < 2; ++kk) bfr[n][kk] = LDSW(Bh, brow + (2 + n) * 16 + r, kk);
    if (more) STAGE_HALF(nxt, 1, 1, kt + 1)
    asm volatile("s_waitcnt lgkmcnt(0)" ::: "memory");
    __builtin_amdgcn_sched_barrier(0);
    __builtin_amdgcn_s_setprio(1);
#pragma unroll
    for (int m = 0; m < 4; ++m)
#pragma unroll
      for (int n = 0; n < 2; ++n)
#pragma unroll
        for (int kk = 0; kk < 2; ++kk)
          acc[4 + m][2 + n] = __builtin_amdgcn_mfma_f32_16x16x32_bf16(af[m][kk], bfr[n][kk],
                                                                      acc[4 + m][2 + n], 0, 0, 0);
    __builtin_amdgcn_s_setprio(0);
    __builtin_amdgcn_s_barrier();
  }

  const int rq = lane >> 4;
#pragma unroll
  for (int m = 0; m < 8; ++m)
#pragma unroll
    for (int n = 0; n < 4; ++n) {
      int col = n0 + wn * 64 + n * 16 + r;
      float bv = bias ? bias[col] : 0.0f;
#pragma unroll
      for (int j = 0; j < 4; ++j) {
        int row = m0 + wm * 128 + m * 16 + rq * 4 + j;
        C[(size_t)row * N + col] = (OutT)(acc[m][n][j] + bv);
      }
    }
#undef STAGE_HALF
#undef LDSW
}

// ---------------------------------------------------------------- RoPE+RMSNorm (q,k) + V transpose
__global__ __launch_bounds__(256) void rope_vt(const __bf16* __restrict__ Y,
                                               const float* __restrict__ cosT,
                                               const float* __restrict__ sinT,
                                               const float* __restrict__ qn,
                                               const float* __restrict__ kn,
                                               __bf16* __restrict__ qat,
                                               __bf16* __restrict__ kat,
                                               __bf16* __restrict__ VT) {
  __shared__ __bf16 tile[32][66];
  if (blockIdx.x < 8192) {
    const int tok = blockIdx.x;
    const int b = tok >> 11, t = tok & 2047;
    const int wv = threadIdx.x >> 6, l = threadIdx.x & 63;
    const __bf16* row = Y + (size_t)tok * 3072;
    const float c = cosT[t * 64 + l], s = sinT[t * 64 + l];
    const float QS = 0.08838834764831845f * 1.4426950408889634f;
#pragma unroll
    for (int i = 0; i < 5; ++i) {
      const int h = wv + i * 4;  // 0..19
      const bool isq = h < 16;
      const int base = isq ? h * 128 : 2048 + (h - 16) * 128;
      union { uint32_t u; __bf16 h2[2]; } p;
      p.u = *(const uint32_t*)(row + base + 2 * l);
      float x1 = (float)p.h2[0], x2 = (float)p.h2[1];
      float v1 = x1 * c - x2 * s;
      float v2 = x1 * s + x2 * c;
      float ss = v1 * v1 + v2 * v2;
#pragma unroll
      for (int o = 32; o >= 1; o >>= 1) ss += __shfl_xor(ss, o, 64);
      float rms = rsqrtf(ss * (1.0f / 128.0f) + 1e-6f);
      if (isq) rms *= QS;
      float w1 = isq ? qn[l] : kn[l];
      float w2 = isq ? qn[64 + l] : kn[64 + l];
      size_t ob = isq ? (((size_t)b * 16 + h) * 2048 + t) * 128
                      : (((size_t)b * 4 + (h - 16)) * 2048 + t) * 128;
      __bf16* dst = isq ? qat : kat;
      dst[ob + l] = (__bf16)(w1 * v1 * rms);
      dst[ob + 64 + l] = (__bf16)(w2 * v2 * rms);
    }
  } else {
    const int i = blockIdx.x - 8192;
    const int t0 = (i & 31) * 64;
    const int d0 = ((i >> 5) & 3) * 32;
    const int bh = i >> 7;
    const int b = bh >> 2, hv = bh & 3;
    const __bf16* src = Y + (size_t)b * 2048 * 3072 + 2560 + hv * 128 + d0;
    const int dd = threadIdx.x & 31, tt = threadIdx.x >> 5;
#pragma unroll
    for (int p = 0; p < 8; ++p) {
      int t = tt + p * 8;
      tile[dd][t] = src[(size_t)(t0 + t) * 3072 + dd];
    }
    __syncthreads();
    __bf16* dst = VT + ((size_t)bh * 128 + d0) * 2048 + t0;
    const int oc = threadIdx.x & 63, orr = threadIdx.x >> 6;
#pragma unroll
    for (int p = 0; p < 8; ++p) {
      int d = orr + p * 4;
      dst[(size_t)d * 2048 + oc] = tile[d][oc];
    }
  }
}

// ---------------------------------------------------------------- flash attention (causal, GQA)
// KVBLK=32, 4 waves x 32 q-rows (QBLK=128), one q-tile per block, grid 1024
// -> 4 blocks/CU (40 KB LDS, 128 VGPR via launch_bounds(256,2)).
__global__ __launch_bounds__(256, 2) void attn12(const __bf16* __restrict__ Q,
                                                 const __bf16* __restrict__ Kg,
                                                 const __bf16* __restrict__ VTg,
                                                 __bf16* __restrict__ ab) {
  __shared__ __align__(16) __bf16 Kt[2][32 * 128];   // 16 KB
  __shared__ __align__(16) __bf16 Vt[2][128 * 32];   // 16 KB
  __shared__ __align__(16) __bf16 Ps[4 * 32 * 32];   // 8 KB
  const int tid = threadIdx.x, lane = tid & 63, wv = tid >> 6;  // wv 0..3
  const int L = blockIdx.x;
  const int xcd = L & 7, slot = L >> 3;                 // slot 0..127
  const int group = xcd * 2 + (slot >> 6);              // 16 (b,hkv) groups
  const int idx = slot & 63;
  const int b = group >> 2, hkv = group & 3;
  const int hq = hkv * 4 + (idx >> 4);
  const int qt = 15 - (idx & 15);                       // long q-tiles dispatch first
  const __bf16* qp = Q + ((size_t)b * 16 + hq) * 2048 * 128;
  const __bf16* kp = Kg + ((size_t)b * 4 + hkv) * 2048 * 128;
  const __bf16* vp = VTg + ((size_t)b * 4 + hkv) * 128 * 2048;
  const int r = lane & 15, g4 = lane >> 4, ks = g4 * 8;

  bf16x8 vone;
#pragma unroll
  for (int e = 0; e < 8; ++e) vone[e] = (__bf16)1.0f;

#define STAGE_TILE(bi, kv0)                                                  \
  {                                                                          \
    __bf16* Kb = &Kt[bi][0];                                                 \
    __bf16* Vb = &Vt[bi][0];                                                 \
    _Pragma("unroll") for (int i = 0; i < 2; ++i) {                          \
      int c = i * 256 + tid;                                                 \
      int row = c >> 4, slot_ = c & 15;                                      \
      int gco = ((slot_ ^ (row & 7)) << 3);                                  \
      stage16(kp + (size_t)((kv0) + row) * 128 + gco, &Kb[c * 8]);           \
    }                                                                        \
    _Pragma("unroll") for (int i = 0; i < 2; ++i) {                          \
      int c = i * 256 + tid;                                                 \
      int row = c >> 2, slot_ = c & 3;                                       \
      int gco = ((slot_ ^ (row & 3)) << 3);                                  \
      stage16(vp + (size_t)row * 2048 + (kv0) + gco, &Vb[c * 8]);            \
    }                                                                        \
  }

  const int q0 = qt * 128 + wv * 32;  // wave owns rows q0..q0+31

  bf16x8 qfA[4], qfB[4];
#pragma unroll
  for (int kk = 0; kk < 4; ++kk) {
    qfA[kk] = *(const bf16x8*)(qp + (size_t)(q0 + r) * 128 + kk * 32 + ks);
    qfB[kk] = *(const bf16x8*)(qp + (size_t)(q0 + 16 + r) * 128 + kk * 32 + ks);
  }

  f32x4 OfA[8] = {}, OfB[8] = {};
  f32x4 LaccA = {}, LaccB = {};
  float mrowA[4] = {-1e30f, -1e30f, -1e30f, -1e30f};
  float mrowB[4] = {-1e30f, -1e30f, -1e30f, -1e30f};

  const int nt = 4 * qt + 4;
  STAGE_TILE(0, 0);
  int cur = 0;
  for (int t = 0; t < nt; ++t) {
    const int kv0 = t * 32;
    if (t + 1 < nt) {
      STAGE_TILE(cur ^ 1, (t + 1) * 32);
      asm volatile("s_waitcnt vmcnt(4)" ::: "memory");
    } else {
      asm volatile("s_waitcnt vmcnt(0)" ::: "memory");
    }
    __builtin_amdgcn_s_barrier();

    const __bf16* Kb = &Kt[cur][0];
    const __bf16* Vb = &Vt[cur][0];

    f32x4 sA[2], sB[2];
    __builtin_amdgcn_s_setprio(1);
#pragma unroll
    for (int kj = 0; kj < 2; ++kj) {
      f32x4 saA = {}, saB = {};
      int krow = kj * 16 + r;
#pragma unroll
      for (int kk = 0; kk < 4; ++kk) {
        int slot_ = (kk * 4 + g4) ^ (r & 7);
        bf16x8 kf = *(const bf16x8*)&Kb[krow * 128 + slot_ * 8];
        saA = __builtin_amdgcn_mfma_f32_16x16x32_bf16(qfA[kk], kf, saA, 0, 0, 0);
        saB = __builtin_amdgcn_mfma_f32_16x16x32_bf16(qfB[kk], kf, saB, 0, 0, 0);
      }
      sA[kj] = saA; sB[kj] = saB;
    }
    __builtin_amdgcn_s_setprio(0);
    if (kv0 + 31 > q0) {
#pragma unroll
      for (int kj = 0; kj < 2; ++kj)
#pragma unroll
        for (int j = 0; j < 4; ++j) {
          int kv = kv0 + kj * 16 + r;
          int qrA = q0 + g4 * 4 + j;
          if (kv > qrA) sA[kj][j] = -1e30f;
          if (kv > qrA + 16) sB[kj][j] = -1e30f;
        }
    }
    float tmA[4], tmB[4];
#pragma unroll
    for (int j = 0; j < 4; ++j) {
      tmA[j] = fmaxf(sA[0][j], sA[1][j]);
      tmB[j] = fmaxf(sB[0][j], sB[1][j]);
    }
    bool need = false;
#pragma unroll
    for (int j = 0; j < 4; ++j)
      need |= (tmA[j] > mrowA[j] + 8.0f) | (tmB[j] > mrowB[j] + 8.0f);
    if (__any(need)) {
#pragma unroll
      for (int o = 8; o >= 1; o >>= 1)
#pragma unroll
        for (int j = 0; j < 4; ++j) {
          tmA[j] = fmaxf(tmA[j], __shfl_xor(tmA[j], o, 64));
          tmB[j] = fmaxf(tmB[j], __shfl_xor(tmB[j], o, 64));
        }
#pragma unroll
      for (int j = 0; j < 4; ++j) {
        float mnA = fmaxf(mrowA[j], tmA[j]);
        float cA = exp2f(mrowA[j] - mnA);
        mrowA[j] = mnA; LaccA[j] *= cA;
        float mnB = fmaxf(mrowB[j], tmB[j]);
        float cB = exp2f(mrowB[j] - mnB);
        mrowB[j] = mnB; LaccB[j] *= cB;
#pragma unroll
        for (int f = 0; f < 8; ++f) { OfA[f][j] *= cA; OfB[f][j] *= cB; }
      }
    }
    __bf16* pw = &Ps[wv * 32 * 32];
#pragma unroll
    for (int kj = 0; kj < 2; ++kj)
#pragma unroll
      for (int j = 0; j < 4; ++j) {
        int kvl = kj * 16 + r;
        int qrA = g4 * 4 + j;
        int slA = (kvl >> 3) ^ (qrA & 3);
        pw[qrA * 32 + slA * 8 + (kvl & 7)] = (__bf16)exp2f(sA[kj][j] - mrowA[j]);
        int qrB = 16 + qrA;
        int slB = (kvl >> 3) ^ (qrB & 3);
        pw[qrB * 32 + slB * 8 + (kvl & 7)] = (__bf16)exp2f(sB[kj][j] - mrowB[j]);
      }
    __builtin_amdgcn_s_setprio(1);
    {
      int sl = g4 ^ (r & 3);
      bf16x8 paA = *(const bf16x8*)&pw[r * 32 + sl * 8];
      bf16x8 paB = *(const bf16x8*)&pw[(16 + r) * 32 + sl * 8];
      LaccA = __builtin_amdgcn_mfma_f32_16x16x32_bf16(paA, vone, LaccA, 0, 0, 0);
      LaccB = __builtin_amdgcn_mfma_f32_16x16x32_bf16(paB, vone, LaccB, 0, 0, 0);
#pragma unroll
      for (int dn = 0; dn < 8; ++dn) {
        int vrow = dn * 16 + r;
        bf16x8 vb = *(const bf16x8*)&Vb[vrow * 32 + ((g4 ^ (r & 3)) << 3)];
        OfA[dn] = __builtin_amdgcn_mfma_f32_16x16x32_bf16(paA, vb, OfA[dn], 0, 0, 0);
        OfB[dn] = __builtin_amdgcn_mfma_f32_16x16x32_bf16(paB, vb, OfB[dn], 0, 0, 0);
      }
    }
    __builtin_amdgcn_s_setprio(0);
    __builtin_amdgcn_s_barrier();
    cur ^= 1;
  }

  float invA[4], invB[4];
#pragma unroll
  for (int j = 0; j < 4; ++j) { invA[j] = 1.0f / LaccA[j]; invB[j] = 1.0f / LaccB[j]; }
#pragma unroll
  for (int dn = 0; dn < 8; ++dn)
#pragma unroll
    for (int j = 0; j < 4; ++j) {
      int rowA = q0 + g4 * 4 + j;
      int d = dn * 16 + r;
      ab[(((size_t)b * 2048 + rowA) * 16 + hq) * 128 + d] = (__bf16)(OfA[dn][j] * invA[j]);
      ab[(((size_t)b * 2048 + rowA + 16) * 16 + hq) * 128 + d] = (__bf16)(OfB[dn][j] * invB[j]);
    }
#undef STAGE_TILE
}

// ---------------------------------------------------------------- fused gate
__global__ __launch_bounds__(256) void gate_fused(const __bf16* __restrict__ a,
                                                  const __bf16* __restrict__ WgB,
                                                  const float* __restrict__ bg,
                                                  __bf16* __restrict__ og) {
  __shared__ __align__(16) __bf16 Wl[128 * 128];
  const int tid = threadIdx.x, lane = tid & 63, wv = tid >> 6;
  const int r = lane & 15, g4 = lane >> 4, ks = g4 * 8;
#pragma unroll
  for (int i = 0; i < 8; ++i) {
    int c = i * 256 + tid;
    int row = c >> 4, slot = c & 15;
    *(bf16x8*)&Wl[row * 128 + ((slot ^ (row & 7)) << 3)] =
        *(const bf16x8*)&WgB[row * 128 + slot * 8];
  }
  __syncthreads();
  const size_t r0 = (size_t)blockIdx.x * 64 + wv * 16;
  bf16x8 af[4];
#pragma unroll
  for (int kk = 0; kk < 4; ++kk)
    af[kk] = *(const bf16x8*)(a + (r0 + r) * 128 + kk * 32 + ks);
  f32x4 acc[8] = {};
#pragma unroll
  for (int dn = 0; dn < 8; ++dn) {
    int row = dn * 16 + r;
#pragma unroll
    for (int kk = 0; kk < 4; ++kk) {
      bf16x8 bf_ = *(const bf16x8*)&Wl[row * 128 + (((kk * 4 + g4) ^ (row & 7)) << 3)];
      acc[dn] = __builtin_amdgcn_mfma_f32_16x16x32_bf16(af[kk], bf_, acc[dn], 0, 0, 0);
    }
  }
#pragma unroll
  for (int dn = 0; dn < 8; ++dn) {
    float bgv = bg[dn * 16 + r];
#pragma unroll
    for (int j = 0; j < 4; ++j) {
      size_t row = r0 + g4 * 4 + j;
      int col = dn * 16 + r;
      float gv = sigmoidf_(acc[dn][j] + bgv);
      float av = (float)a[row * 128 + col];
      og[row * 128 + col] = (__bf16)(av * gv);
    }
  }
}

// ---------------------------------------------------------------- launch
extern "C" void kernel_launch(void* const* d_in, const int* in_sizes, int n_in,
                              void* d_out, int out_size, void* d_ws, size_t ws_size,
                              hipStream_t stream) {
  const float* x    = (const float*)d_in[0];
  const float* Wq   = (const float*)d_in[1];
  const float* bq   = (const float*)d_in[2];
  const float* Wk   = (const float*)d_in[3];
  const float* bk   = (const float*)d_in[4];
  const float* Wv   = (const float*)d_in[5];
  const float* bv   = (const float*)d_in[6];
  const float* qn   = (const float*)d_in[7];
  const float* kn   = (const float*)d_in[8];
  const float* Wg   = (const float*)d_in[9];
  const float* bg   = (const float*)d_in[10];
  const float* Wo   = (const float*)d_in[11];
  const float* bo   = (const float*)d_in[12];
  const float* cosT = (const float*)d_in[13];
  const float* sinT = (const float*)d_in[14];

  char* ws = (char*)d_ws;
  constexpr size_t OFF_WQKV = 0;                                   // 3072x2048 bf16
  constexpr size_t OFF_WO   = OFF_WQKV + 3072ull * 2048 * 2;       // 2048x2048 bf16
  constexpr size_t OFF_WG   = OFF_WO + 2048ull * 2048 * 2;         // 128x128 bf16
  constexpr size_t OFF_BQKV = OFF_WG + 128ull * 128 * 2;           // 3072 f32 (+pad)
  constexpr size_t OFF_XB   = OFF_BQKV + 16384;                    // 8192x2048 bf16 (reused: OG)
  constexpr size_t OFF_Y    = OFF_XB + 8192ull * 2048 * 2;         // 8192x3072 bf16
  constexpr size_t OFF_QAT  = OFF_Y + 8192ull * 3072 * 2;          // (B,HQ,T,D) bf16
  constexpr size_t OFF_KAT  = OFF_QAT + 4ull * 16 * 2048 * 128 * 2;
  constexpr size_t OFF_VT   = OFF_KAT + 4ull * 4 * 2048 * 128 * 2; // (B,HKV,D,T) bf16
  constexpr size_t OFF_AB   = OFF_VT + 4ull * 4 * 2048 * 128 * 2;  // (B,T,HQ,D) bf16

  __bf16* WQKVb = (__bf16*)(ws + OFF_WQKV);
  __bf16* WOb   = (__bf16*)(ws + OFF_WO);
  __bf16* WGb   = (__bf16*)(ws + OFF_WG);
  float*  BQKV  = (float*)(ws + OFF_BQKV);
  __bf16* XB    = (__bf16*)(ws + OFF_XB);
  __bf16* Y     = (__bf16*)(ws + OFF_Y);
  __bf16* QAT   = (__bf16*)(ws + OFF_QAT);
  __bf16* KAT   = (__bf16*)(ws + OFF_KAT);
  __bf16* VT    = (__bf16*)(ws + OFF_VT);
  __bf16* ABuf  = (__bf16*)(ws + OFF_AB);
  __bf16* OGB   = (__bf16*)(ws + OFF_XB);   // reuse XB (dead after QKV GEMM)

  prep<<<26643, 256, 0, stream>>>(x, Wq, Wk, Wv, Wo, Wg, bq, bk, bv,
                                  XB, WQKVb, WOb, WGb, BQKV);

  // QKV projection: 256^2 8-phase, 384 blocks
  gemm256<__bf16><<<384, 512, 0, stream>>>(XB, WQKVb, BQKV, Y, 8192, 3072, 2048, 12);

  // RoPE+RMSNorm (q,k; Q pre-scaled) + V transpose
  rope_vt<<<10240, 256, 0, stream>>>(Y, cosT, sinT, qn, kn, QAT, KAT, VT);

  // flash attention: KVBLK=32, 1024 blocks, 4 blocks/CU, 128-VGPR bound
  attn12<<<1024, 256, 0, stream>>>(QAT, KAT, VT, ABuf);

  // fused gate
  gate_fused<<<2048, 256, 0, stream>>>(ABuf, WGb, bg, OGB);

  // output projection: 256^2, 256 blocks = 1 full round
  gemm256<float><<<256, 512, 0, stream>>>(OGB, WOb, bo, (float*)d_out, 8192, 2048, 2048, 8);
}

// Round 18
// 384.828 us; speedup vs baseline: 2.4762x; 1.1455x over previous
//
#include <hip/hip_runtime.h>
#include <hip/hip_bf16.h>
#include <math.h>

typedef __attribute__((ext_vector_type(8))) __bf16 bf16x8;
typedef __attribute__((ext_vector_type(4))) float f32x4;

// ---------------------------------------------------------------- helpers
__device__ __forceinline__ void stage16(const void* g, void* l) {
#if __has_builtin(__builtin_amdgcn_global_load_lds)
  __builtin_amdgcn_global_load_lds(
      (const __attribute__((address_space(1))) void*)g,
      (__attribute__((address_space(3))) void*)l, 16, 0, 0);
#else
  *(int4*)l = *(const int4*)g;
#endif
}

__device__ __forceinline__ float sigmoidf_(float x) {
  return 1.0f / (1.0f + __expf(-x));
}

__device__ __forceinline__ void f2b4(const float* __restrict__ s, __bf16* __restrict__ d) {
  float4 v = *(const float4*)s;
  union { __bf16 h[4]; int2 p; } u;
  u.h[0] = (__bf16)v.x; u.h[1] = (__bf16)v.y;
  u.h[2] = (__bf16)v.z; u.h[3] = (__bf16)v.w;
  *(int2*)d = u.p;
}

// ---------------------------------------------------------------- prep: all f32->bf16 + bias concat
__global__ __launch_bounds__(256) void prep(const float* __restrict__ x,
                                            const float* __restrict__ Wq,
                                            const float* __restrict__ Wk,
                                            const float* __restrict__ Wv,
                                            const float* __restrict__ Wo,
                                            const float* __restrict__ Wg,
                                            const float* __restrict__ bq,
                                            const float* __restrict__ bk,
                                            const float* __restrict__ bv,
                                            __bf16* __restrict__ XB,
                                            __bf16* __restrict__ WQKVb,
                                            __bf16* __restrict__ WOb,
                                            __bf16* __restrict__ WGb,
                                            float* __restrict__ BQKV) {
  int c = blockIdx.x * 256 + threadIdx.x;
  if (c >= 6820608) return;
  if (c < 4194304) {
    f2b4(x + (size_t)c * 4, XB + (size_t)c * 4);
  } else if (c < 5242880) {
    int e = (c - 4194304) * 4;  f2b4(Wq + e, WQKVb + e);
  } else if (c < 5505024) {
    int e = (c - 5242880) * 4;  f2b4(Wk + e, WQKVb + 4194304 + e);
  } else if (c < 5767168) {
    int e = (c - 5505024) * 4;  f2b4(Wv + e, WQKVb + 5242880 + e);
  } else if (c < 6815744) {
    int e = (c - 5767168) * 4;  f2b4(Wo + e, WOb + e);
  } else if (c < 6819840) {
    int e = (c - 6815744) * 4;  f2b4(Wg + e, WGb + e);
  } else {
    int e = (c - 6819840) * 4;
    float4 v;
    if (e < 2048)      v = *(const float4*)(bq + e);
    else if (e < 2560) v = *(const float4*)(bk + (e - 2048));
    else               v = *(const float4*)(bv + (e - 2560));
    *(float4*)(BQKV + e) = v;
  }
}

// ---------------------------------------------------------------- GEMM 256x256, 8-phase (out proj)
template <typename OutT>
__global__ __launch_bounds__(512, 1) void gemm256(const __bf16* __restrict__ A,
                                                  const __bf16* __restrict__ Bm,
                                                  const float* __restrict__ bias,
                                                  OutT* __restrict__ C,
                                                  int M, int N, int K, int gx) {
  __shared__ __align__(16) __bf16 Sm[2][2][2][128 * 64];
  const int tid = threadIdx.x, lane = tid & 63, wid = tid >> 6;
  const int wm = wid >> 2, wn = wid & 3;
  const int r = lane & 15, g4 = lane >> 4;
  const int nwg = gridDim.x, qx = nwg >> 3;
  const int wg = (blockIdx.x & 7) * qx + (blockIdx.x >> 3);
  const int m0 = (wg / gx) * 256, n0 = (wg % gx) * 256;

  f32x4 acc[8][4] = {};
  const int NT = K >> 6;

#define STAGE_HALF(buf, which, half, kt)                                          \
  {                                                                               \
    const __bf16* sp_ = (which) ? Bm : A;                                         \
    const int base_ = ((which) ? n0 : m0) + (half) * 128;                         \
    const int k0_ = (kt) << 6;                                                    \
    __bf16* dp_ = &Sm[buf][which][half][0];                                       \
    _Pragma("unroll") for (int i_ = 0; i_ < 2; ++i_) {                            \
      int c_ = i_ * 512 + tid;                                                    \
      int row_ = c_ >> 3, slot_ = c_ & 7;                                         \
      stage16(sp_ + (size_t)(base_ + row_) * K + k0_ + ((slot_ ^ (row_ & 7)) << 3), \
              dp_ + c_ * 8);                                                      \
    }                                                                             \
  }
#define LDSW(base, row, kk) \
  (*(const bf16x8*)&(base)[(row) * 64 + ((((kk) * 4 + g4) ^ ((row) & 7)) << 3)])

  STAGE_HALF(0, 0, 0, 0) STAGE_HALF(0, 0, 1, 0) STAGE_HALF(0, 1, 0, 0) STAGE_HALF(0, 1, 1, 0)

  const int brow = (wn & 1) * 64;
  bf16x8 af[4][2], bfr[2][2];

  for (int kt = 0; kt < NT; ++kt) {
    const int cur = kt & 1, nxt = cur ^ 1;
    const bool more = (kt + 1) < NT;
    const __bf16* Ah = &Sm[cur][0][wm][0];
    const __bf16* Bh = &Sm[cur][1][wn >> 1][0];

    if (more) STAGE_HALF(nxt, 0, 0, kt + 1)
    if (more) { asm volatile("s_waitcnt vmcnt(2)" ::: "memory"); }
    else      { asm volatile("s_waitcnt vmcnt(0)" ::: "memory"); }
    __builtin_amdgcn_s_barrier();
    asm volatile("" ::: "memory");
#pragma unroll
    for (int m = 0; m < 4; ++m)
#pragma unroll
      for (int kk = 0; kk < 2; ++kk) af[m][kk] = LDSW(Ah, m * 16 + r, kk);
#pragma unroll
    for (int n = 0; n < 2; ++n)
#pragma unroll
      for (int kk = 0; kk < 2; ++kk) bfr[n][kk] = LDSW(Bh, brow + n * 16 + r, kk);
    asm volatile("s_waitcnt lgkmcnt(0)" ::: "memory");
    __builtin_amdgcn_sched_barrier(0);
    __builtin_amdgcn_s_setprio(1);
#pragma unroll
    for (int m = 0; m < 4; ++m)
#pragma unroll
      for (int n = 0; n < 2; ++n)
#pragma unroll
        for (int kk = 0; kk < 2; ++kk)
          acc[m][n] = __builtin_amdgcn_mfma_f32_16x16x32_bf16(af[m][kk], bfr[n][kk],
                                                              acc[m][n], 0, 0, 0);
    __builtin_amdgcn_s_setprio(0);
    __builtin_amdgcn_s_barrier();

#pragma unroll
    for (int n = 0; n < 2; ++n)
#pragma unroll
      for (int kk = 0; kk < 2; ++kk) bfr[n][kk] = LDSW(Bh, brow + (2 + n) * 16 + r, kk);
    if (more) STAGE_HALF(nxt, 0, 1, kt + 1)
    asm volatile("s_waitcnt lgkmcnt(0)" ::: "memory");
    __builtin_amdgcn_sched_barrier(0);
    __builtin_amdgcn_s_setprio(1);
#pragma unroll
    for (int m = 0; m < 4; ++m)
#pragma unroll
      for (int n = 0; n < 2; ++n)
#pragma unroll
        for (int kk = 0; kk < 2; ++kk)
          acc[m][2 + n] = __builtin_amdgcn_mfma_f32_16x16x32_bf16(af[m][kk], bfr[n][kk],
                                                                  acc[m][2 + n], 0, 0, 0);
    __builtin_amdgcn_s_setprio(0);
    __builtin_amdgcn_s_barrier();

#pragma unroll
    for (int m = 0; m < 4; ++m)
#pragma unroll
      for (int kk = 0; kk < 2; ++kk) af[m][kk] = LDSW(Ah, (4 + m) * 16 + r, kk);
#pragma unroll
    for (int n = 0; n < 2; ++n)
#pragma unroll
      for (int kk = 0; kk < 2; ++kk) bfr[n][kk] = LDSW(Bh, brow + n * 16 + r, kk);
    if (more) STAGE_HALF(nxt, 1, 0, kt + 1)
    asm volatile("s_waitcnt lgkmcnt(0)" ::: "memory");
    __builtin_amdgcn_sched_barrier(0);
    __builtin_amdgcn_s_setprio(1);
#pragma unroll
    for (int m = 0; m < 4; ++m)
#pragma unroll
      for (int n = 0; n < 2; ++n)
#pragma unroll
        for (int kk = 0; kk < 2; ++kk)
          acc[4 + m][n] = __builtin_amdgcn_mfma_f32_16x16x32_bf16(af[m][kk], bfr[n][kk],
                                                                  acc[4 + m][n], 0, 0, 0);
    __builtin_amdgcn_s_setprio(0);
    __builtin_amdgcn_s_barrier();

#pragma unroll
    for (int n = 0; n < 2; ++n)
#pragma unroll
      for (int kk = 0; kk < 2; ++kk) bfr[n][kk] = LDSW(Bh, brow + (2 + n) * 16 + r, kk);
    if (more) STAGE_HALF(nxt, 1, 1, kt + 1)
    asm volatile("s_waitcnt lgkmcnt(0)" ::: "memory");
    __builtin_amdgcn_sched_barrier(0);
    __builtin_amdgcn_s_setprio(1);
#pragma unroll
    for (int m = 0; m < 4; ++m)
#pragma unroll
      for (int n = 0; n < 2; ++n)
#pragma unroll
        for (int kk = 0; kk < 2; ++kk)
          acc[4 + m][2 + n] = __builtin_amdgcn_mfma_f32_16x16x32_bf16(af[m][kk], bfr[n][kk],
                                                                      acc[4 + m][2 + n], 0, 0, 0);
    __builtin_amdgcn_s_setprio(0);
    __builtin_amdgcn_s_barrier();
  }

  const int rq = lane >> 4;
#pragma unroll
  for (int m = 0; m < 8; ++m)
#pragma unroll
    for (int n = 0; n < 4; ++n) {
      int col = n0 + wn * 64 + n * 16 + r;
      float bv = bias ? bias[col] : 0.0f;
#pragma unroll
      for (int j = 0; j < 4; ++j) {
        int row = m0 + wm * 128 + m * 16 + rq * 4 + j;
        C[(size_t)row * N + col] = (OutT)(acc[m][n][j] + bv);
      }
    }
#undef STAGE_HALF
#undef LDSW
}

// ---------------------------------------------------------------- GEMM 128x256, 4-phase (QKV)
__global__ __launch_bounds__(512, 1) void gemm128(const __bf16* __restrict__ A,
                                                  const __bf16* __restrict__ Bm,
                                                  const float* __restrict__ bias,
                                                  __bf16* __restrict__ C,
                                                  int M, int N, int K, int gx) {
  __shared__ __align__(16) __bf16 Sm[2][3][128 * 64];
  const int tid = threadIdx.x, lane = tid & 63, wid = tid >> 6;
  const int wm = wid >> 2, wn = wid & 3;
  const int r = lane & 15, g4 = lane >> 4;
  const int nwg = gridDim.x, qx = nwg >> 3;
  const int wg = (blockIdx.x & 7) * qx + (blockIdx.x >> 3);
  const int m0 = (wg / gx) * 128, n0 = (wg % gx) * 256;

  f32x4 acc[4][4] = {};
  const int NT = K >> 6;

#define STAGE_SEG(buf, seg, sp, rowbase, kt)                                        \
  {                                                                                 \
    __bf16* dp_ = &Sm[buf][seg][0];                                                 \
    const int k0_ = (kt) << 6;                                                      \
    _Pragma("unroll") for (int i_ = 0; i_ < 2; ++i_) {                              \
      int c_ = i_ * 512 + tid;                                                      \
      int row_ = c_ >> 3, slot_ = c_ & 7;                                           \
      stage16((sp) + (size_t)((rowbase) + row_) * K + k0_ + ((slot_ ^ (row_ & 7)) << 3), \
              dp_ + c_ * 8);                                                        \
    }                                                                               \
  }
#define LDSW(base, row, kk) \
  (*(const bf16x8*)&(base)[(row) * 64 + ((((kk) * 4 + g4) ^ ((row) & 7)) << 3)])
#define MFMA8(nq)                                                                   \
  asm volatile("s_waitcnt lgkmcnt(0)" ::: "memory");                                \
  __builtin_amdgcn_sched_barrier(0);                                                \
  __builtin_amdgcn_s_setprio(1);                                                    \
  _Pragma("unroll") for (int m = 0; m < 4; ++m)                                     \
    _Pragma("unroll") for (int kk = 0; kk < 2; ++kk)                                \
      acc[m][nq] = __builtin_amdgcn_mfma_f32_16x16x32_bf16(af[m][kk], bfr[kk],      \
                                                           acc[m][nq], 0, 0, 0);    \
  __builtin_amdgcn_s_setprio(0);

  STAGE_SEG(0, 0, A, m0, 0) STAGE_SEG(0, 1, Bm, n0, 0) STAGE_SEG(0, 2, Bm, n0 + 128, 0)

  const int bseg = 1 + (wn >> 1);
  const int brow = (wn & 1) * 64;
  bf16x8 af[4][2], bfr[2];

  for (int kt = 0; kt < NT; ++kt) {
    const int cur = kt & 1, nxt = cur ^ 1;
    const bool more = (kt + 1) < NT;
    const __bf16* Ah = &Sm[cur][0][0];
    const __bf16* Bh = &Sm[cur][bseg][0];

    if (more) { STAGE_SEG(nxt, 0, A, m0, kt + 1)
                asm volatile("s_waitcnt vmcnt(2)" ::: "memory"); }
    else      { asm volatile("s_waitcnt vmcnt(0)" ::: "memory"); }
    __builtin_amdgcn_s_barrier();
    asm volatile("" ::: "memory");
#pragma unroll
    for (int m = 0; m < 4; ++m)
#pragma unroll
      for (int kk = 0; kk < 2; ++kk) af[m][kk] = LDSW(Ah, wm * 64 + m * 16 + r, kk);
#pragma unroll
    for (int kk = 0; kk < 2; ++kk) bfr[kk] = LDSW(Bh, brow + r, kk);
    MFMA8(0)

#pragma unroll
    for (int kk = 0; kk < 2; ++kk) bfr[kk] = LDSW(Bh, brow + 16 + r, kk);
    if (more) STAGE_SEG(nxt, 1, Bm, n0, kt + 1)
    MFMA8(1)

#pragma unroll
    for (int kk = 0; kk < 2; ++kk) bfr[kk] = LDSW(Bh, brow + 32 + r, kk);
    if (more) STAGE_SEG(nxt, 2, Bm, n0 + 128, kt + 1)
    MFMA8(2)

#pragma unroll
    for (int kk = 0; kk < 2; ++kk) bfr[kk] = LDSW(Bh, brow + 48 + r, kk);
    MFMA8(3)
    __builtin_amdgcn_s_barrier();
  }

  const int rq = lane >> 4;
#pragma unroll
  for (int m = 0; m < 4; ++m)
#pragma unroll
    for (int n = 0; n < 4; ++n) {
      int col = n0 + wn * 64 + n * 16 + r;
      float bv = bias ? bias[col] : 0.0f;
#pragma unroll
      for (int j = 0; j < 4; ++j) {
        int row = m0 + wm * 64 + m * 16 + rq * 4 + j;
        C[(size_t)row * N + col] = (__bf16)(acc[m][n][j] + bv);
      }
    }
#undef STAGE_SEG
#undef LDSW
#undef MFMA8
}

// ---------------------------------------------------------------- RoPE+RMSNorm (q,k) + V transpose
__global__ __launch_bounds__(256) void rope_vt(const __bf16* __restrict__ Y,
                                               const float* __restrict__ cosT,
                                               const float* __restrict__ sinT,
                                               const float* __restrict__ qn,
                                               const float* __restrict__ kn,
                                               __bf16* __restrict__ qat,
                                               __bf16* __restrict__ kat,
                                               __bf16* __restrict__ VT) {
  __shared__ __bf16 tile[32][66];
  if (blockIdx.x < 8192) {
    const int tok = blockIdx.x;
    const int b = tok >> 11, t = tok & 2047;
    const int wv = threadIdx.x >> 6, l = threadIdx.x & 63;
    const __bf16* row = Y + (size_t)tok * 3072;
    const float c = cosT[t * 64 + l], s = sinT[t * 64 + l];
    const float QS = 0.08838834764831845f * 1.4426950408889634f;
#pragma unroll
    for (int i = 0; i < 5; ++i) {
      const int h = wv + i * 4;  // 0..19
      const bool isq = h < 16;
      const int base = isq ? h * 128 : 2048 + (h - 16) * 128;
      union { uint32_t u; __bf16 h2[2]; } p;
      p.u = *(const uint32_t*)(row + base + 2 * l);
      float x1 = (float)p.h2[0], x2 = (float)p.h2[1];
      float v1 = x1 * c - x2 * s;
      float v2 = x1 * s + x2 * c;
      float ss = v1 * v1 + v2 * v2;
#pragma unroll
      for (int o = 32; o >= 1; o >>= 1) ss += __shfl_xor(ss, o, 64);
      float rms = rsqrtf(ss * (1.0f / 128.0f) + 1e-6f);
      if (isq) rms *= QS;
      float w1 = isq ? qn[l] : kn[l];
      float w2 = isq ? qn[64 + l] : kn[64 + l];
      size_t ob = isq ? (((size_t)b * 16 + h) * 2048 + t) * 128
                      : (((size_t)b * 4 + (h - 16)) * 2048 + t) * 128;
      __bf16* dst = isq ? qat : kat;
      dst[ob + l] = (__bf16)(w1 * v1 * rms);
      dst[ob + 64 + l] = (__bf16)(w2 * v2 * rms);
    }
  } else {
    const int i = blockIdx.x - 8192;
    const int t0 = (i & 31) * 64;
    const int d0 = ((i >> 5) & 3) * 32;
    const int bh = i >> 7;
    const int b = bh >> 2, hv = bh & 3;
    const __bf16* src = Y + (size_t)b * 2048 * 3072 + 2560 + hv * 128 + d0;
    const int dd = threadIdx.x & 31, tt = threadIdx.x >> 5;
#pragma unroll
    for (int p = 0; p < 8; ++p) {
      int t = tt + p * 8;
      tile[dd][t] = src[(size_t)(t0 + t) * 3072 + dd];
    }
    __syncthreads();
    __bf16* dst = VT + ((size_t)bh * 128 + d0) * 2048 + t0;
    const int oc = threadIdx.x & 63, orr = threadIdx.x >> 6;
#pragma unroll
    for (int p = 0; p < 8; ++p) {
      int d = orr + p * 4;
      dst[(size_t)d * 2048 + oc] = tile[d][oc];
    }
  }
}

// ---------------------------------------------------------------- flash attention (causal, GQA)
// KVBLK=64, 4 waves x 32 q-rows (two 16-row halves share every K/V fragment
// read). exp2 softmax, MFMA row-sum, lazy max. Best measured config (R14).
__global__ __launch_bounds__(256, 2) void attn11(const __bf16* __restrict__ Q,
                                                 const __bf16* __restrict__ Kg,
                                                 const __bf16* __restrict__ VTg,
                                                 __bf16* __restrict__ ab) {
  __shared__ __align__(16) __bf16 Kt[2][64 * 128];
  __shared__ __align__(16) __bf16 Vt[2][128 * 64];
  __shared__ __align__(16) __bf16 Ps[4 * 32 * 64];
  const int tid = threadIdx.x, lane = tid & 63, wv = tid >> 6;
  const int L = blockIdx.x;
  const int xcd = L & 7, slot = L >> 3;
  const int group = xcd * 2 + (slot >> 5);
  const int idx = slot & 31;
  const int b = group >> 2, hkv = group & 3;
  const int hq = hkv * 4 + (idx >> 3);
  const int p = idx & 7;
  const __bf16* qp = Q + ((size_t)b * 16 + hq) * 2048 * 128;
  const __bf16* kp = Kg + ((size_t)b * 4 + hkv) * 2048 * 128;
  const __bf16* vp = VTg + ((size_t)b * 4 + hkv) * 128 * 2048;
  const int r = lane & 15, g4 = lane >> 4, ks = g4 * 8;

  bf16x8 vone;
#pragma unroll
  for (int e = 0; e < 8; ++e) vone[e] = (__bf16)1.0f;

#define STAGE_TILE(bi, kv0)                                                  \
  {                                                                          \
    __bf16* Kb = &Kt[bi][0];                                                 \
    __bf16* Vb = &Vt[bi][0];                                                 \
    _Pragma("unroll") for (int i = 0; i < 4; ++i) {                          \
      int c = i * 256 + tid;                                                 \
      int row = c >> 4, slot_ = c & 15;                                      \
      int gco = ((slot_ ^ (row & 7)) << 3);                                  \
      stage16(kp + (size_t)((kv0) + row) * 128 + gco, &Kb[c * 8]);           \
    }                                                                        \
    _Pragma("unroll") for (int i = 0; i < 4; ++i) {                          \
      int c = i * 256 + tid;                                                 \
      int row = c >> 3, slot_ = c & 7;                                       \
      int gco = ((slot_ ^ (row & 7)) << 3);                                  \
      stage16(vp + (size_t)row * 2048 + (kv0) + gco, &Vb[c * 8]);            \
    }                                                                        \
  }

  for (int half_ = 0; half_ < 2; ++half_) {
    const int qt = half_ == 0 ? (15 - p) : p;
    const int q0 = qt * 128 + wv * 32;

    bf16x8 qfA[4], qfB[4];
#pragma unroll
    for (int kk = 0; kk < 4; ++kk) {
      qfA[kk] = *(const bf16x8*)(qp + (size_t)(q0 + r) * 128 + kk * 32 + ks);
      qfB[kk] = *(const bf16x8*)(qp + (size_t)(q0 + 16 + r) * 128 + kk * 32 + ks);
    }

    f32x4 OfA[8] = {}, OfB[8] = {};
    f32x4 LaccA = {}, LaccB = {};
    float mrowA[4] = {-1e30f, -1e30f, -1e30f, -1e30f};
    float mrowB[4] = {-1e30f, -1e30f, -1e30f, -1e30f};

    const int nt = 2 * qt + 2;
    STAGE_TILE(0, 0);
    int cur = 0;
    for (int t = 0; t < nt; ++t) {
      const int kv0 = t * 64;
      if (t + 1 < nt) {
        STAGE_TILE(cur ^ 1, (t + 1) * 64);
        asm volatile("s_waitcnt vmcnt(8)" ::: "memory");
      } else {
        asm volatile("s_waitcnt vmcnt(0)" ::: "memory");
      }
      __builtin_amdgcn_s_barrier();

      const __bf16* Kb = &Kt[cur][0];
      const __bf16* Vb = &Vt[cur][0];

      f32x4 sA[4], sB[4];
      __builtin_amdgcn_s_setprio(1);
#pragma unroll
      for (int kj = 0; kj < 4; ++kj) {
        f32x4 saA = {}, saB = {};
        int krow = kj * 16 + r;
#pragma unroll
        for (int kk = 0; kk < 4; ++kk) {
          int slot_ = (kk * 4 + g4) ^ (r & 7);
          bf16x8 kf = *(const bf16x8*)&Kb[krow * 128 + slot_ * 8];
          saA = __builtin_amdgcn_mfma_f32_16x16x32_bf16(qfA[kk], kf, saA, 0, 0, 0);
          saB = __builtin_amdgcn_mfma_f32_16x16x32_bf16(qfB[kk], kf, saB, 0, 0, 0);
        }
        sA[kj] = saA; sB[kj] = saB;
      }
      __builtin_amdgcn_s_setprio(0);
      if (kv0 + 63 > q0) {
#pragma unroll
        for (int kj = 0; kj < 4; ++kj)
#pragma unroll
          for (int j = 0; j < 4; ++j) {
            int kv = kv0 + kj * 16 + r;
            int qrA = q0 + g4 * 4 + j;
            if (kv > qrA) sA[kj][j] = -1e30f;
            if (kv > qrA + 16) sB[kj][j] = -1e30f;
          }
      }
      float tmA[4], tmB[4];
#pragma unroll
      for (int j = 0; j < 4; ++j) {
        tmA[j] = fmaxf(fmaxf(sA[0][j], sA[1][j]), fmaxf(sA[2][j], sA[3][j]));
        tmB[j] = fmaxf(fmaxf(sB[0][j], sB[1][j]), fmaxf(sB[2][j], sB[3][j]));
      }
      bool need = false;
#pragma unroll
      for (int j = 0; j < 4; ++j)
        need |= (tmA[j] > mrowA[j] + 8.0f) | (tmB[j] > mrowB[j] + 8.0f);
      if (__any(need)) {
#pragma unroll
        for (int o = 8; o >= 1; o >>= 1)
#pragma unroll
          for (int j = 0; j < 4; ++j) {
            tmA[j] = fmaxf(tmA[j], __shfl_xor(tmA[j], o, 64));
            tmB[j] = fmaxf(tmB[j], __shfl_xor(tmB[j], o, 64));
          }
#pragma unroll
        for (int j = 0; j < 4; ++j) {
          float mnA = fmaxf(mrowA[j], tmA[j]);
          float cA = exp2f(mrowA[j] - mnA);
          mrowA[j] = mnA; LaccA[j] *= cA;
          float mnB = fmaxf(mrowB[j], tmB[j]);
          float cB = exp2f(mrowB[j] - mnB);
          mrowB[j] = mnB; LaccB[j] *= cB;
#pragma unroll
          for (int f = 0; f < 8; ++f) { OfA[f][j] *= cA; OfB[f][j] *= cB; }
        }
      }
      __bf16* pw = &Ps[wv * 32 * 64];
#pragma unroll
      for (int kj = 0; kj < 4; ++kj)
#pragma unroll
        for (int j = 0; j < 4; ++j) {
          int kvl = kj * 16 + r;
          int qrA = g4 * 4 + j;
          int slA = (kvl >> 3) ^ (qrA & 7);
          pw[qrA * 64 + slA * 8 + (kvl & 7)] = (__bf16)exp2f(sA[kj][j] - mrowA[j]);
          int qrB = 16 + qrA;
          pw[qrB * 64 + slA * 8 + (kvl & 7)] = (__bf16)exp2f(sB[kj][j] - mrowB[j]);
        }
      __builtin_amdgcn_s_setprio(1);
#pragma unroll
      for (int kvj = 0; kvj < 2; ++kvj) {
        int sl = (kvj * 4 + g4) ^ (r & 7);
        bf16x8 paA = *(const bf16x8*)&pw[r * 64 + sl * 8];
        bf16x8 paB = *(const bf16x8*)&pw[(16 + r) * 64 + sl * 8];
        LaccA = __builtin_amdgcn_mfma_f32_16x16x32_bf16(paA, vone, LaccA, 0, 0, 0);
        LaccB = __builtin_amdgcn_mfma_f32_16x16x32_bf16(paB, vone, LaccB, 0, 0, 0);
#pragma unroll
        for (int dn = 0; dn < 8; ++dn) {
          bf16x8 vb = *(const bf16x8*)&Vb[(dn * 16 + r) * 64 + sl * 8];
          OfA[dn] = __builtin_amdgcn_mfma_f32_16x16x32_bf16(paA, vb, OfA[dn], 0, 0, 0);
          OfB[dn] = __builtin_amdgcn_mfma_f32_16x16x32_bf16(paB, vb, OfB[dn], 0, 0, 0);
        }
      }
      __builtin_amdgcn_s_setprio(0);
      __builtin_amdgcn_s_barrier();
      cur ^= 1;
    }

    float invA[4], invB[4];
#pragma unroll
    for (int j = 0; j < 4; ++j) { invA[j] = 1.0f / LaccA[j]; invB[j] = 1.0f / LaccB[j]; }
#pragma unroll
    for (int dn = 0; dn < 8; ++dn)
#pragma unroll
      for (int j = 0; j < 4; ++j) {
        int rowA = q0 + g4 * 4 + j;
        int d = dn * 16 + r;
        ab[(((size_t)b * 2048 + rowA) * 16 + hq) * 128 + d] = (__bf16)(OfA[dn][j] * invA[j]);
        ab[(((size_t)b * 2048 + rowA + 16) * 16 + hq) * 128 + d] = (__bf16)(OfB[dn][j] * invB[j]);
      }
  }
#undef STAGE_TILE
}

// ---------------------------------------------------------------- fused gate
__global__ __launch_bounds__(256) void gate_fused(const __bf16* __restrict__ a,
                                                  const __bf16* __restrict__ WgB,
                                                  const float* __restrict__ bg,
                                                  __bf16* __restrict__ og) {
  __shared__ __align__(16) __bf16 Wl[128 * 128];
  const int tid = threadIdx.x, lane = tid & 63, wv = tid >> 6;
  const int r = lane & 15, g4 = lane >> 4, ks = g4 * 8;
#pragma unroll
  for (int i = 0; i < 8; ++i) {
    int c = i * 256 + tid;
    int row = c >> 4, slot = c & 15;
    *(bf16x8*)&Wl[row * 128 + ((slot ^ (row & 7)) << 3)] =
        *(const bf16x8*)&WgB[row * 128 + slot * 8];
  }
  __syncthreads();
  const size_t r0 = (size_t)blockIdx.x * 64 + wv * 16;
  bf16x8 af[4];
#pragma unroll
  for (int kk = 0; kk < 4; ++kk)
    af[kk] = *(const bf16x8*)(a + (r0 + r) * 128 + kk * 32 + ks);
  f32x4 acc[8] = {};
#pragma unroll
  for (int dn = 0; dn < 8; ++dn) {
    int row = dn * 16 + r;
#pragma unroll
    for (int kk = 0; kk < 4; ++kk) {
      bf16x8 bf_ = *(const bf16x8*)&Wl[row * 128 + (((kk * 4 + g4) ^ (row & 7)) << 3)];
      acc[dn] = __builtin_amdgcn_mfma_f32_16x16x32_bf16(af[kk], bf_, acc[dn], 0, 0, 0);
    }
  }
#pragma unroll
  for (int dn = 0; dn < 8; ++dn) {
    float bgv = bg[dn * 16 + r];
#pragma unroll
    for (int j = 0; j < 4; ++j) {
      size_t row = r0 + g4 * 4 + j;
      int col = dn * 16 + r;
      float gv = sigmoidf_(acc[dn][j] + bgv);
      float av = (float)a[row * 128 + col];
      og[row * 128 + col] = (__bf16)(av * gv);
    }
  }
}

// ---------------------------------------------------------------- launch
extern "C" void kernel_launch(void* const* d_in, const int* in_sizes, int n_in,
                              void* d_out, int out_size, void* d_ws, size_t ws_size,
                              hipStream_t stream) {
  const float* x    = (const float*)d_in[0];
  const float* Wq   = (const float*)d_in[1];
  const float* bq   = (const float*)d_in[2];
  const float* Wk   = (const float*)d_in[3];
  const float* bk   = (const float*)d_in[4];
  const float* Wv   = (const float*)d_in[5];
  const float* bv   = (const float*)d_in[6];
  const float* qn   = (const float*)d_in[7];
  const float* kn   = (const float*)d_in[8];
  const float* Wg   = (const float*)d_in[9];
  const float* bg   = (const float*)d_in[10];
  const float* Wo   = (const float*)d_in[11];
  const float* bo   = (const float*)d_in[12];
  const float* cosT = (const float*)d_in[13];
  const float* sinT = (const float*)d_in[14];

  char* ws = (char*)d_ws;
  constexpr size_t OFF_WQKV = 0;                                   // 3072x2048 bf16
  constexpr size_t OFF_WO   = OFF_WQKV + 3072ull * 2048 * 2;       // 2048x2048 bf16
  constexpr size_t OFF_WG   = OFF_WO + 2048ull * 2048 * 2;         // 128x128 bf16
  constexpr size_t OFF_BQKV = OFF_WG + 128ull * 128 * 2;           // 3072 f32 (+pad)
  constexpr size_t OFF_XB   = OFF_BQKV + 16384;                    // 8192x2048 bf16 (reused: OG)
  constexpr size_t OFF_Y    = OFF_XB + 8192ull * 2048 * 2;         // 8192x3072 bf16
  constexpr size_t OFF_QAT  = OFF_Y + 8192ull * 3072 * 2;          // (B,HQ,T,D) bf16
  constexpr size_t OFF_KAT  = OFF_QAT + 4ull * 16 * 2048 * 128 * 2;
  constexpr size_t OFF_VT   = OFF_KAT + 4ull * 4 * 2048 * 128 * 2; // (B,HKV,D,T) bf16
  constexpr size_t OFF_AB   = OFF_VT + 4ull * 4 * 2048 * 128 * 2;  // (B,T,HQ,D) bf16

  __bf16* WQKVb = (__bf16*)(ws + OFF_WQKV);
  __bf16* WOb   = (__bf16*)(ws + OFF_WO);
  __bf16* WGb   = (__bf16*)(ws + OFF_WG);
  float*  BQKV  = (float*)(ws + OFF_BQKV);
  __bf16* XB    = (__bf16*)(ws + OFF_XB);
  __bf16* Y     = (__bf16*)(ws + OFF_Y);
  __bf16* QAT   = (__bf16*)(ws + OFF_QAT);
  __bf16* KAT   = (__bf16*)(ws + OFF_KAT);
  __bf16* VT    = (__bf16*)(ws + OFF_VT);
  __bf16* ABuf  = (__bf16*)(ws + OFF_AB);
  __bf16* OGB   = (__bf16*)(ws + OFF_XB);   // reuse XB (dead after QKV GEMM)

  prep<<<26643, 256, 0, stream>>>(x, Wq, Wk, Wv, Wo, Wg, bq, bk, bv,
                                  XB, WQKVb, WOb, WGb, BQKV);

  // QKV projection: 128x256 tiles, 4-phase, 768 blocks = 3 full CU rounds
  gemm128<<<768, 512, 0, stream>>>(XB, WQKVb, BQKV, Y, 8192, 3072, 2048, 12);

  // RoPE+RMSNorm (q,k; Q pre-scaled) + V transpose
  rope_vt<<<10240, 256, 0, stream>>>(Y, cosT, sinT, qn, kn, QAT, KAT, VT);

  // flash attention: KVBLK=64, 4 waves x 32 q-rows (best measured config)
  attn11<<<512, 256, 0, stream>>>(QAT, KAT, VT, ABuf);

  // fused gate
  gate_fused<<<2048, 256, 0, stream>>>(ABuf, WGb, bg, OGB);

  // output projection: 256^2, 256 blocks = 1 full round
  gemm256<float><<<256, 512, 0, stream>>>(OGB, WOb, bo, (float*)d_out, 8192, 2048, 2048, 8);
}